// Round 16
// baseline (208.321 us; speedup 1.0000x reference)
//
#include <hip/hip_runtime.h>

#define NN 384
#define RR 8
#define NR (NN * RR)   // 3072
#define IPAD 385       // padded i-stride for A2c (breaks c-dimension bank aliasing)
#define GSTR 72        // Gh row stride in f16 (144B rows -> bank spread)

typedef _Float16 half4v __attribute__((ext_vector_type(4)));
typedef _Float16 half8v __attribute__((ext_vector_type(8)));
typedef float f32x4 __attribute__((ext_vector_type(4)));

// out[b,i] = sum_{a,b2,c} A[a,i,b2]*Bf[b2,j_b,c]*C[c,k_b,a]
// G[b2,a] = sum_c Bf[b2,j,c]*C[c,k,a];  out[b,i] = sum_p A2[i,p]*G[p], p=a*8+b2.
// r16 = r13 with MFMA operands SWAPPED: D = A2_tile x G^T. LDS reads are
// byte-identical to r13 (A/B fragment maps exchange roles); D now lands with
// 4 consecutive i per lane -> one dwordx4 store (12 stores/wave/batch vs 48).
__global__ __launch_bounds__(512, 4)
void dtn_mfma16s(const float* __restrict__ A, const float* __restrict__ Bf,
                 const float* __restrict__ C, const int* __restrict__ x,
                 float* __restrict__ out)
{
    __shared__ __align__(16) _Float16 A2c[8 * IPAD * 8];   // 49280 B
    __shared__ __align__(16) _Float16 Gh[64 * GSTR];       //  9216 B  (58.5 KB total)

    const int t = threadIdx.x;
    const long b0 = (long)blockIdx.x * 256;

    // ---- Stage A2c[(a*IPAD+i)*8+e] = f16(A[a*NR + i*8 + e]); 3072 chunks, 6 iters.
    #pragma unroll
    for (int it = 0; it < 6; ++it) {
        const int idx = t + it * 512;     // 0..3071
        const int i = idx >> 3;
        const int a = idx & 7;
        const float4* src = reinterpret_cast<const float4*>(A + (size_t)a * NR + (size_t)i * RR);
        const float4 f0 = src[0];
        const float4 f1 = src[1];
        half8v h;
        h[0] = (_Float16)f0.x; h[1] = (_Float16)f0.y; h[2] = (_Float16)f0.z; h[3] = (_Float16)f0.w;
        h[4] = (_Float16)f1.x; h[5] = (_Float16)f1.y; h[6] = (_Float16)f1.z; h[7] = (_Float16)f1.w;
        *reinterpret_cast<half8v*>(&A2c[(size_t)(a * IPAD + i) * 8]) = h;
    }

    const int lane = t & 63;
    const int w    = t >> 6;     // wave 0..7
    const int mt   = w & 3;      // pair-16-tile within the 64-pair batch
    const int nh   = w >> 2;     // i-half: [0,192) or [192,384)
    const int a16  = lane & 15;
    const int q    = lane >> 4;  // 0..3

    #pragma unroll 1
    for (int bt = 0; bt < 4; ++bt) {
        __syncthreads();   // Gh free to overwrite (also covers staging on bt=0)

        // ---- G phase (math identical to proven r10/r13): thread -> (bl=t>>3, a=t&7)
        {
            const int bl = t >> 3;
            const int a  = t & 7;
            const long pair = b0 + bt * 64 + bl;
            const int j = x[2 * pair];
            const int k = x[2 * pair + 1];
            const float* Bj = Bf + (size_t)j * RR;       // Bf[b2,j,c] at Bj[b2*NR + c]
            const float* Ck = C + (size_t)k * RR + a;    // C[c,k,a]   at Ck[c*NR]
            float ck[8];
            #pragma unroll
            for (int c = 0; c < 8; ++c)
                ck[c] = Ck[(size_t)c * NR];
            half8v h;
            #pragma unroll
            for (int b2 = 0; b2 < 8; ++b2) {
                const float4* br = reinterpret_cast<const float4*>(Bj + (size_t)b2 * NR);
                const float4 r0 = br[0];
                const float4 r1 = br[1];
                const float s = r0.x * ck[0] + r0.y * ck[1] + r0.z * ck[2] + r0.w * ck[3]
                              + r1.x * ck[4] + r1.y * ck[5] + r1.z * ck[6] + r1.w * ck[7];
                h[b2] = (_Float16)s;
            }
            *reinterpret_cast<half8v*>(&Gh[bl * GSTR + a * 8]) = h;   // p = a*8 + b2
        }
        __syncthreads();

        // ---- G fragments (now the B-operand: col = a16 -> pair, k = 16kt+4q+e).
        // Same LDS addresses as r13's af reads.
        const half4v gf0 = *reinterpret_cast<const half4v*>(&Gh[(mt * 16 + a16) * GSTR +  0 + 4 * q]);
        const half4v gf1 = *reinterpret_cast<const half4v*>(&Gh[(mt * 16 + a16) * GSTR + 16 + 4 * q]);
        const half4v gf2 = *reinterpret_cast<const half4v*>(&Gh[(mt * 16 + a16) * GSTR + 32 + 4 * q]);
        const half4v gf3 = *reinterpret_cast<const half4v*>(&Gh[(mt * 16 + a16) * GSTR + 48 + 4 * q]);

        const long prow = b0 + bt * 64 + mt * 16 + a16;   // this lane's output pair-row

        // ---- 12 i-tiles of 16; A-operand (row = a16 -> i, k = 16kt+4q+e) reads are
        // r13's bf reads unchanged. D: row 4q+r = i-offset, col a16 = pair -> dwordx4.
        #pragma unroll 2
        for (int nt = 0; nt < 12; ++nt) {
            const int i0 = nh * 192 + nt * 16;
            const int col = i0 + a16;          // A-fragment row index within A2c
            f32x4 acc = {0.f, 0.f, 0.f, 0.f};
            const half4v bf0 = *reinterpret_cast<const half4v*>(
                &A2c[(size_t)((0 + (q >> 1)) * IPAD + col) * 8 + 4 * (q & 1)]);
            acc = __builtin_amdgcn_mfma_f32_16x16x16f16(bf0, gf0, acc, 0, 0, 0);
            const half4v bf1 = *reinterpret_cast<const half4v*>(
                &A2c[(size_t)((2 + (q >> 1)) * IPAD + col) * 8 + 4 * (q & 1)]);
            acc = __builtin_amdgcn_mfma_f32_16x16x16f16(bf1, gf1, acc, 0, 0, 0);
            const half4v bf2 = *reinterpret_cast<const half4v*>(
                &A2c[(size_t)((4 + (q >> 1)) * IPAD + col) * 8 + 4 * (q & 1)]);
            acc = __builtin_amdgcn_mfma_f32_16x16x16f16(bf2, gf2, acc, 0, 0, 0);
            const half4v bf3 = *reinterpret_cast<const half4v*>(
                &A2c[(size_t)((6 + (q >> 1)) * IPAD + col) * 8 + 4 * (q & 1)]);
            acc = __builtin_amdgcn_mfma_f32_16x16x16f16(bf3, gf3, acc, 0, 0, 0);

            // One 16B store: out[prow][i0 + 4q .. 4q+3]
            *reinterpret_cast<f32x4*>(out + (size_t)prow * NN + i0 + 4 * q) = acc;
        }
    }
}

extern "C" void kernel_launch(void* const* d_in, const int* in_sizes, int n_in,
                              void* d_out, int out_size, void* d_ws, size_t ws_size,
                              hipStream_t stream) {
    const float* A  = (const float*)d_in[0];
    const float* Bf = (const float*)d_in[1];
    const float* C  = (const float*)d_in[2];
    const int*   x  = (const int*)d_in[3];
    float* out = (float*)d_out;
    const int B = in_sizes[3] / 2;           // 524288
    dtn_mfma16s<<<B / 256, 512, 0, stream>>>(A, Bf, C, x, out);
}

// Round 17
// 165.086 us; speedup vs baseline: 1.2619x; 1.2619x over previous
//
#include <hip/hip_runtime.h>

#define NN 384
#define RR 8
#define NR (NN * RR)   // 3072
#define IPAD 385       // padded i-stride for A2c (breaks c-dimension bank aliasing)
#define GSTR 72        // Gh row stride in f16 (144B rows -> bank spread)

typedef _Float16 half4v __attribute__((ext_vector_type(4)));
typedef _Float16 half8v __attribute__((ext_vector_type(8)));
typedef float f32x4 __attribute__((ext_vector_type(4)));

// out[b,i] = sum_{a,b2,c} A[a,i,b2]*Bf[b2,j_b,c]*C[c,k_b,a]
// G[b2,a] = sum_c Bf[b2,j,c]*C[c,k,a];  out[b,i] = sum_p A2[i,p]*G[p], p=a*8+b2.
// r17: wave-autonomous version of r13. Each wave owns 16 pairs end-to-end:
// computes G (r4 per-lane map) into wave-PRIVATE LDS, reads its own fragments,
// MFMAs, stores. One block-wide barrier total (after A2 staging) vs r13's 8.
__global__ __launch_bounds__(512, 4)
void dtn_mfma16w(const float* __restrict__ A, const float* __restrict__ Bf,
                 const float* __restrict__ C, const int* __restrict__ x,
                 float* __restrict__ out)
{
    __shared__ __align__(16) _Float16 A2c[8 * IPAD * 8];   // 49280 B
    __shared__ __align__(16) _Float16 Gh[8 * 16 * GSTR];   // 18432 B (wave-private 2304B each)

    const int t = threadIdx.x;
    const long b0 = (long)blockIdx.x * 128;   // 128 pairs per block (8 waves x 16)

    // ---- Stage A2c[(a*IPAD+i)*8+e] = f16(A[a*NR + i*8 + e]); 3072 chunks, 6 iters.
    #pragma unroll
    for (int it = 0; it < 6; ++it) {
        const int idx = t + it * 512;     // 0..3071
        const int i = idx >> 3;
        const int a = idx & 7;
        const float4* src = reinterpret_cast<const float4*>(A + (size_t)a * NR + (size_t)i * RR);
        const float4 f0 = src[0];
        const float4 f1 = src[1];
        half8v h;
        h[0] = (_Float16)f0.x; h[1] = (_Float16)f0.y; h[2] = (_Float16)f0.z; h[3] = (_Float16)f0.w;
        h[4] = (_Float16)f1.x; h[5] = (_Float16)f1.y; h[6] = (_Float16)f1.z; h[7] = (_Float16)f1.w;
        *reinterpret_cast<half8v*>(&A2c[(size_t)(a * IPAD + i) * 8]) = h;
    }
    __syncthreads();   // the ONLY block-wide barrier

    const int lane = t & 63;
    const int w    = t >> 6;                       // wave 0..7 owns pairs b0+w*16..+15
    _Float16* Ghw  = &Gh[w * 16 * GSTR];           // wave-private G region

    // ---- G phase (r4-proven per-lane map): lane -> pair bl = lane>>2, a0 = (lane&3)*2.
    {
        const int bl = lane >> 2;
        const int a0 = (lane & 3) * 2;
        const long pair = b0 + w * 16 + bl;
        const int j = x[2 * pair];
        const int k = x[2 * pair + 1];
        const float* Bj = Bf + (size_t)j * RR;       // Bf[b2,j,c] at Bj[b2*NR + c]
        const float* Ck = C + (size_t)k * RR + a0;   // C[c,k,a0+d] at Ck[c*NR + d]
        float2 ck[8];
        #pragma unroll
        for (int c = 0; c < 8; ++c)
            ck[c] = *reinterpret_cast<const float2*>(Ck + (size_t)c * NR);
        half8v h0, h1;
        #pragma unroll
        for (int b2 = 0; b2 < 8; ++b2) {
            const float4* br = reinterpret_cast<const float4*>(Bj + (size_t)b2 * NR);
            const float4 r0 = br[0];
            const float4 r1 = br[1];
            const float s0 = r0.x * ck[0].x + r0.y * ck[1].x + r0.z * ck[2].x + r0.w * ck[3].x
                           + r1.x * ck[4].x + r1.y * ck[5].x + r1.z * ck[6].x + r1.w * ck[7].x;
            const float s1 = r0.x * ck[0].y + r0.y * ck[1].y + r0.z * ck[2].y + r0.w * ck[3].y
                           + r1.x * ck[4].y + r1.y * ck[5].y + r1.z * ck[6].y + r1.w * ck[7].y;
            h0[b2] = (_Float16)s0;
            h1[b2] = (_Float16)s1;
        }
        *reinterpret_cast<half8v*>(&Ghw[bl * GSTR + a0 * 8]) = h0;       // p = a0*8 + b2
        *reinterpret_cast<half8v*>(&Ghw[bl * GSTR + a0 * 8 + 8]) = h1;   // p = (a0+1)*8 + b2
    }
    // Wave-private RAW on LDS: compiler emits lgkmcnt wait; no barrier needed.

    const int a16 = lane & 15;
    const int q   = lane >> 4;   // 0..3

    // ---- A-fragments (r13 map): G-row = a16 (pair), k-windows 0/16/32/48 (+4q).
    const half4v af0 = *reinterpret_cast<const half4v*>(&Ghw[a16 * GSTR +  0 + 4 * q]);
    const half4v af1 = *reinterpret_cast<const half4v*>(&Ghw[a16 * GSTR + 16 + 4 * q]);
    const half4v af2 = *reinterpret_cast<const half4v*>(&Ghw[a16 * GSTR + 32 + 4 * q]);
    const half4v af3 = *reinterpret_cast<const half4v*>(&Ghw[a16 * GSTR + 48 + 4 * q]);

    const long prow0 = b0 + w * 16 + 4 * q;    // D row base (pair) for this lane

    // ---- 24 N-tiles of 16 i; B-frag (r13 map): A2[col=n0+a16][k=16kt+4q+e],
    //      p = 16kt+4q+e -> chunk c = 2kt+(q>>1), elem = 4*(q&1)+e.
    #pragma unroll 2
    for (int nt = 0; nt < 24; ++nt) {
        const int col = nt * 16 + a16;
        f32x4 acc = {0.f, 0.f, 0.f, 0.f};
        const half4v bf0 = *reinterpret_cast<const half4v*>(
            &A2c[(size_t)((0 + (q >> 1)) * IPAD + col) * 8 + 4 * (q & 1)]);
        acc = __builtin_amdgcn_mfma_f32_16x16x16f16(af0, bf0, acc, 0, 0, 0);
        const half4v bf1 = *reinterpret_cast<const half4v*>(
            &A2c[(size_t)((2 + (q >> 1)) * IPAD + col) * 8 + 4 * (q & 1)]);
        acc = __builtin_amdgcn_mfma_f32_16x16x16f16(af1, bf1, acc, 0, 0, 0);
        const half4v bf2 = *reinterpret_cast<const half4v*>(
            &A2c[(size_t)((4 + (q >> 1)) * IPAD + col) * 8 + 4 * (q & 1)]);
        acc = __builtin_amdgcn_mfma_f32_16x16x16f16(af2, bf2, acc, 0, 0, 0);
        const half4v bf3 = *reinterpret_cast<const half4v*>(
            &A2c[(size_t)((6 + (q >> 1)) * IPAD + col) * 8 + 4 * (q & 1)]);
        acc = __builtin_amdgcn_mfma_f32_16x16x16f16(af3, bf3, acc, 0, 0, 0);

        float* op = out + (size_t)prow0 * NN + col;
        op[0]            = acc[0];
        op[(size_t)NN]   = acc[1];
        op[(size_t)2*NN] = acc[2];
        op[(size_t)3*NN] = acc[3];
    }
}

extern "C" void kernel_launch(void* const* d_in, const int* in_sizes, int n_in,
                              void* d_out, int out_size, void* d_ws, size_t ws_size,
                              hipStream_t stream) {
    const float* A  = (const float*)d_in[0];
    const float* Bf = (const float*)d_in[1];
    const float* C  = (const float*)d_in[2];
    const int*   x  = (const int*)d_in[3];
    float* out = (float*)d_out;
    const int B = in_sizes[3] / 2;           // 524288
    dtn_mfma16w<<<B / 128, 512, 0, stream>>>(A, Bf, C, x, out);
}